// Round 5
// baseline (747.897 us; speedup 1.0000x reference)
//
#include <hip/hip_runtime.h>

// CostVolume2D: N=8, C=128, H=96, W=224, D=4 -> 81 channels.
// out[n, dy*9+dx, h, w] = mean_c f1[n,c,h,w] * f2[n,c,h+dy-4,w+dx-4] (0 if OOB)
//
// Round 9: single-wave workgroups, ZERO barriers, minimal LDS.
// Evidence trail: R4/R5 pinned at 133-139us (28% VALU, ~2500cy/channel wall
// vs ~600cy issue) regardless of barrier flavor -> the 3-wave barrier convoy
// + ~4 co-resident blocks is structural. R8 showed residency caps at
// ~32KB-pool/LDS_size (offered 7.9 blocks/CU, got 4.7 with 6.6KB LDS).
// This version:
//  - block = 1 wave (64 thr) handling one (tile 32x16, dy) pair; grid
//    3024 blocks = 11.8 fully-independent waves/CU; no wave waits for any
//    other, so SIMD slots fill whenever ANY wave is ready.
//  - LDS = single 2816B buffer (16 rows x 44 stride), private to the wave:
//    write(c+1) -> read(c+1) is same-wave lgkm ordering (compiler-managed),
//    no s_barrier anywhere. 32K/2816 = 11 blocks -> LDS can't cap residency.
//  - staging loads contiguous (10 float4 granules per row; 3 masked
//    instructions/wave), NOT the R6 per-lane gather.
//  - 2-body register prefetch: stA/stB (f2 staging) and faA/faB (f1),
//    slack ~2 channels for HBM/L2 latency.
// Per thread: 8 w-px x 9 dx = 72 fp32 acc, 72 FMA/channel (proven R5 body).

constexpr int Cn = 128;
constexpr int Hh = 96;
constexpr int Ww = 224;
constexpr int HW = Hh * Ww;       // 21504
constexpr int TILE_H = 16;
constexpr int TILE_W = 32;
constexpr int NROW = 16;          // staged rows: single dy needs exactly 16
constexpr int F2S  = 44;          // row stride: 2-way read aliasing (free)
constexpr int CT   = NROW * F2S;  // 704 floats = 2816 B
constexpr int NG   = 10;          // float4 granules per row (40 staged cols)
constexpr int SLOTS = NROW * NG;  // 160 slots; thread t covers t, t+64, t+128

__global__ __launch_bounds__(64, 3)
void costvol_kernel(const float* __restrict__ f1g, const float* __restrict__ f2g,
                    float* __restrict__ outg) {
    __shared__ float lds[CT];          // single buffer, wave-private

    const int b    = blockIdx.x;
    const int xcd  = b & 7;            // consecutive block IDs round-robin XCDs
    const int j    = b >> 3;           // 0..377
    const int dy   = j % 9;
    const int tp   = j / 9;            // 0..41
    const int tile = tp * 8 + xcd;     // a tile's 9 dy-waves -> same XCD
    const int wt   = tile % 7;
    const int ht   = (tile / 7) % 6;
    const int n    = tile / 42;

    const int h0 = ht * TILE_H;
    const int w0 = wt * TILE_W;

    const int lane = threadIdx.x;
    const int gx   = lane & 3;         // 8 w px: w = w0 + 8*gx + (0..7)
    const int gy   = lane >> 2;        // h row: h = h0 + gy
    const int hA   = h0 + gy;
    const int wA   = w0 + 8 * gx;

    const size_t nbase = (size_t)n * Cn * HW;
    const float* f1n = f1g + nbase;
    const float* f2n = f2g + nbase;

    // ---- staging geometry: slot s -> row s/10, granule s%10 ----
    // f2 row y = h0 + dy - 4 + r ; col x = w0 - 4 + 4*g (granule fully in/out)
    bool sAct[3], sVal[3];
    const float* f2sp[3];
    int sLds[3];
#pragma unroll
    for (int k = 0; k < 3; ++k) {
        const int s = lane + 64 * k;
        sAct[k] = (s < SLOTS);
        const int r = s / NG;
        const int g = s - r * NG;
        const int y = h0 + dy - 4 + r;
        const int x = w0 - 4 + 4 * g;
        sVal[k] = sAct[k] && (y >= 0) && (y < Hh) && (x >= 0) && (x < Ww);
        f2sp[k] = f2n + (sVal[k] ? (y * Ww + x) : 0);
        sLds[k] = r * F2S + 4 * g;
    }

    const int f1off = hA * Ww + wA;
    const float* f1b = f1n + f1off;
    const int ldsr   = gy * F2S + 8 * gx;   // frag window base (16B aligned)
    const float* ldr = &lds[ldsr];

    float4 acc[2][9];
#pragma unroll
    for (int p = 0; p < 2; ++p)
#pragma unroll
        for (int dx = 0; dx < 9; ++dx)
            acc[p][dx] = make_float4(0.f, 0.f, 0.f, 0.f);

    const float4 z4 = make_float4(0.f, 0.f, 0.f, 0.f);

    // ---- prologue ----
    // channel 0 staged + frags(0) read; prefetch f2(1),f2(2), f1(0),f1(1)
    float4 stA[3], stB[3];
#pragma unroll
    for (int k = 0; k < 3; ++k) {
        const float4 v = sVal[k] ? *(const float4*)(f2sp[k]) : z4;
        if (sAct[k]) *(float4*)(&lds[sLds[k]]) = v;
    }
#pragma unroll
    for (int k = 0; k < 3; ++k)
        stA[k] = sVal[k] ? *(const float4*)(f2sp[k] + HW) : z4;           // f2(1)
#pragma unroll
    for (int k = 0; k < 3; ++k)
        stB[k] = sVal[k] ? *(const float4*)(f2sp[k] + 2 * HW) : z4;       // f2(2)
    float4 faA0 = *(const float4*)(f1b);                                  // f1(0)
    float4 faA1 = *(const float4*)(f1b + 4);
    float4 faB0 = *(const float4*)(f1b + HW);                             // f1(1)
    float4 faB1 = *(const float4*)(f1b + HW + 4);

    float4 qA0 = *(const float4*)(ldr);                                   // frags(0)
    float4 qA1 = *(const float4*)(ldr + 4);
    float4 qA2 = *(const float4*)(ldr + 8);
    float4 qA3 = *(const float4*)(ldr + 12);
    float4 qB0, qB1, qB2, qB3;

#pragma unroll 1
    for (int cc = 0; cc < Cn; cc += 2) {
        // ============ even body: channel cc ============
        {
            // write f2(cc+1) into the buffer (frags(cc) already in regs)
#pragma unroll
            for (int k = 0; k < 3; ++k)
                if (sAct[k]) *(float4*)(&lds[sLds[k]]) = stA[k];

            const float4 a0 = faA0, a1 = faA1;                 // f1(cc)
            const int c3 = (cc + 3 < Cn) ? (cc + 3) : (Cn - 1);
            const int c2 = (cc + 2 < Cn) ? (cc + 2) : (Cn - 1);
#pragma unroll
            for (int k = 0; k < 3; ++k)
                stA[k] = sVal[k] ? *(const float4*)(f2sp[k] + (size_t)c3 * HW) : z4;
            faA0 = *(const float4*)(f1b + (size_t)c2 * HW);
            faA1 = *(const float4*)(f1b + (size_t)c2 * HW + 4);

            const float wv[16] = {qA0.x, qA0.y, qA0.z, qA0.w,
                                  qA1.x, qA1.y, qA1.z, qA1.w,
                                  qA2.x, qA2.y, qA2.z, qA2.w,
                                  qA3.x, qA3.y, qA3.z, qA3.w};
#pragma unroll
            for (int dx = 0; dx < 9; ++dx) {
                acc[0][dx].x += a0.x * wv[dx + 0];
                acc[0][dx].y += a0.y * wv[dx + 1];
                acc[0][dx].z += a0.z * wv[dx + 2];
                acc[0][dx].w += a0.w * wv[dx + 3];
                acc[1][dx].x += a1.x * wv[dx + 4];
                acc[1][dx].y += a1.y * wv[dx + 5];
                acc[1][dx].z += a1.z * wv[dx + 6];
                acc[1][dx].w += a1.w * wv[dx + 7];
            }
            // frags(cc+1): after this body's write (same-wave lgkm ordering)
            qB0 = *(const float4*)(ldr);
            qB1 = *(const float4*)(ldr + 4);
            qB2 = *(const float4*)(ldr + 8);
            qB3 = *(const float4*)(ldr + 12);
        }
        // ============ odd body: channel cc+1 ============
        {
#pragma unroll
            for (int k = 0; k < 3; ++k)
                if (sAct[k]) *(float4*)(&lds[sLds[k]]) = stB[k];  // f2(cc+2)

            const float4 a0 = faB0, a1 = faB1;                 // f1(cc+1)
            const int c4 = (cc + 4 < Cn) ? (cc + 4) : (Cn - 1);
            const int c3b = (cc + 3 < Cn) ? (cc + 3) : (Cn - 1);
#pragma unroll
            for (int k = 0; k < 3; ++k)
                stB[k] = sVal[k] ? *(const float4*)(f2sp[k] + (size_t)c4 * HW) : z4;
            faB0 = *(const float4*)(f1b + (size_t)c3b * HW);
            faB1 = *(const float4*)(f1b + (size_t)c3b * HW + 4);

            const float wv[16] = {qB0.x, qB0.y, qB0.z, qB0.w,
                                  qB1.x, qB1.y, qB1.z, qB1.w,
                                  qB2.x, qB2.y, qB2.z, qB2.w,
                                  qB3.x, qB3.y, qB3.z, qB3.w};
#pragma unroll
            for (int dx = 0; dx < 9; ++dx) {
                acc[0][dx].x += a0.x * wv[dx + 0];
                acc[0][dx].y += a0.y * wv[dx + 1];
                acc[0][dx].z += a0.z * wv[dx + 2];
                acc[0][dx].w += a0.w * wv[dx + 3];
                acc[1][dx].x += a1.x * wv[dx + 4];
                acc[1][dx].y += a1.y * wv[dx + 5];
                acc[1][dx].z += a1.z * wv[dx + 6];
                acc[1][dx].w += a1.w * wv[dx + 7];
            }
            // frags(cc+2)
            qA0 = *(const float4*)(ldr);
            qA1 = *(const float4*)(ldr + 4);
            qA2 = *(const float4*)(ldr + 8);
            qA3 = *(const float4*)(ldr + 12);
        }
    }

    // ---- writeout: 2 x 9 float4 per thread, coalesced 16B stores ----
    const float sc = 1.0f / 128.0f;
    float* ob = outg + (size_t)n * 81 * HW + (size_t)hA * Ww + wA;
#pragma unroll
    for (int dx = 0; dx < 9; ++dx) {
        const int k = dy * 9 + dx;
#pragma unroll
        for (int p = 0; p < 2; ++p) {
            float4 v = acc[p][dx];
            v.x *= sc; v.y *= sc; v.z *= sc; v.w *= sc;
            *(float4*)(ob + (size_t)k * HW + 4 * p) = v;
        }
    }
}

extern "C" void kernel_launch(void* const* d_in, const int* in_sizes, int n_in,
                              void* d_out, int out_size, void* d_ws, size_t ws_size,
                              hipStream_t stream) {
    const float* f1 = (const float*)d_in[0];
    const float* f2 = (const float*)d_in[1];
    float* out = (float*)d_out;
    // grid: 336 tiles x 9 dy, swizzled so a tile's 9 waves share an XCD
    costvol_kernel<<<dim3(3024), dim3(64), 0, stream>>>(f1, f2, out);
}

// Round 7
// 744.986 us; speedup vs baseline: 1.0039x; 1.0039x over previous
//
#include <hip/hip_runtime.h>

// CostVolume2D: N=8, C=128, H=96, W=224, D=4 -> 81 channels.
// out[n, dy*9+dx, h, w] = mean_c f1[n,c,h,w] * f2[n,c,h+dy-4,w+dx-4] (0 if OOB)
//
// Round 11 = round 10 resubmitted verbatim (round-10 bench died with an
// infrastructure error: "MI355X container failed twice" -- no dispatch ran;
// source audit found no OOB/illegal construct, so the hypothesis is untested).
//
// Round 10 rationale: R9's barrier-free 1-wave structure, sized to FIT the
// register cap. R9 post-mortem: body needed ~170 VGPR but hipcc capped at 84
// -> 1.18GB scratch spill (628us). Cross-round cap law: cap ~= 512/(2*arg)
// (R7: arg6 -> 40; R9: arg3 -> 84). R9 PROVED the structure: single-buffer
// no-barrier LDS (same-wave ds ordering) is correct, and 1-wave blocks reach
// ~11 waves/CU residency.
// This round:
//  - TILE_W 16: per-thread 4 w-px x 9 dx = 36 acc; total live state ~100
//    VGPR. __launch_bounds__(64,2) -> cap 128 by the law (256 if literal).
//  - grid 672 tiles x 9 dy = 6048 one-wave blocks = 23.6 waves/CU offered;
//    LDS single buffer 16 rows x 28 stride = 1792B -> neither LDS nor VGPR
//    caps below ~16 waves/CU. All waves mutually independent, zero barriers.
//  - staging: 96 contiguous float4 granules (16 rows x 6), 1.5 slots/thread;
//    2-deep register prefetch for f2-staging and f1 (R9 schedule: write
//    staged(c+1) -> FMA(c) -> read frags(c+1), same-wave ds ordering).

constexpr int Cn = 128;
constexpr int Hh = 96;
constexpr int Ww = 224;
constexpr int HW = Hh * Ww;       // 21504
constexpr int TILE_H = 16;
constexpr int TILE_W = 16;
constexpr int NROW = 16;          // staged rows: single dy needs exactly 16
constexpr int F2S  = 28;          // row stride floats: gy,gy+8 alias = 2-way (free)
constexpr int CT   = NROW * F2S;  // 448 floats = 1792 B
constexpr int NG   = 6;           // float4 granules per row (24 staged cols)
constexpr int SLOTS = NROW * NG;  // 96 slots; thread t covers t and t+64

__global__ __launch_bounds__(64, 2)
void costvol_kernel(const float* __restrict__ f1g, const float* __restrict__ f2g,
                    float* __restrict__ outg) {
    __shared__ float lds[CT];          // single buffer, wave-private

    const int b    = blockIdx.x;
    const int xcd  = b & 7;            // consecutive block IDs round-robin XCDs
    const int j    = b >> 3;           // 0..755
    const int dy   = j % 9;
    const int tp   = j / 9;            // 0..83
    const int tile = tp * 8 + xcd;     // a tile's 9 dy-waves -> same XCD
    const int wt   = tile % 14;
    const int ht   = (tile / 14) % 6;
    const int n    = tile / 84;

    const int h0 = ht * TILE_H;
    const int w0 = wt * TILE_W;

    const int lane = threadIdx.x;
    const int gx   = lane & 3;         // 4 w px: w = w0 + 4*gx + (0..3)
    const int gy   = lane >> 2;        // h row: h = h0 + gy
    const int hA   = h0 + gy;
    const int wA   = w0 + 4 * gx;

    const size_t nbase = (size_t)n * Cn * HW;
    const float* f1n = f1g + nbase;
    const float* f2n = f2g + nbase;

    // ---- staging geometry: slot s -> row s/6, granule s%6 ----
    // f2 row y = h0 + dy - 4 + r ; col x = w0 - 4 + 4*g (granule fully in/out)
    bool sAct[2], sVal[2];
    const float* f2sp[2];
    int sLds[2];
#pragma unroll
    for (int k = 0; k < 2; ++k) {
        const int s = lane + 64 * k;
        sAct[k] = (s < SLOTS);
        const int r = s / NG;
        const int g = s - r * NG;
        const int y = h0 + dy - 4 + r;
        const int x = w0 - 4 + 4 * g;
        sVal[k] = sAct[k] && (y >= 0) && (y < Hh) && (x >= 0) && (x < Ww);
        f2sp[k] = f2n + (sVal[k] ? (y * Ww + x) : 0);
        sLds[k] = r * F2S + 4 * g;
    }

    const float* f1b = f1n + hA * Ww + wA;
    const float* ldr = &lds[gy * F2S + 4 * gx];   // 12-float window base

    float4 acc[9];
#pragma unroll
    for (int dx = 0; dx < 9; ++dx)
        acc[dx] = make_float4(0.f, 0.f, 0.f, 0.f);

    const float4 z4 = make_float4(0.f, 0.f, 0.f, 0.f);

    // ---- prologue: stage ch0; prime 2-deep pipeline ----
    float4 stA[2], stB[2];
#pragma unroll
    for (int k = 0; k < 2; ++k) {
        const float4 v = sVal[k] ? *(const float4*)(f2sp[k]) : z4;
        if (sAct[k]) *(float4*)(&lds[sLds[k]]) = v;
    }
#pragma unroll
    for (int k = 0; k < 2; ++k)
        stA[k] = sVal[k] ? *(const float4*)(f2sp[k] + HW) : z4;       // f2(1)
#pragma unroll
    for (int k = 0; k < 2; ++k)
        stB[k] = sVal[k] ? *(const float4*)(f2sp[k] + 2 * HW) : z4;   // f2(2)
    float4 faA = *(const float4*)(f1b);                               // f1(0)
    float4 faB = *(const float4*)(f1b + HW);                          // f1(1)

    float4 qA0 = *(const float4*)(ldr);                               // frags(0)
    float4 qA1 = *(const float4*)(ldr + 4);
    float4 qA2 = *(const float4*)(ldr + 8);
    float4 qB0, qB1, qB2;

#pragma unroll 1
    for (int cc = 0; cc < Cn; cc += 2) {
        // ============ even body: channel cc ============
        {
            // write f2(cc+1) into buffer (frags(cc) already in regs; same-wave
            // ds-pipe ordering makes write-after-read safe, no barrier)
#pragma unroll
            for (int k = 0; k < 2; ++k)
                if (sAct[k]) *(float4*)(&lds[sLds[k]]) = stA[k];

            const float4 a0 = faA;                             // f1(cc)
            const int c3 = (cc + 3 < Cn) ? (cc + 3) : (Cn - 1);
            const int c2 = (cc + 2 < Cn) ? (cc + 2) : (Cn - 1);
#pragma unroll
            for (int k = 0; k < 2; ++k)
                stA[k] = sVal[k] ? *(const float4*)(f2sp[k] + (size_t)c3 * HW) : z4;
            faA = *(const float4*)(f1b + (size_t)c2 * HW);

            const float wv[12] = {qA0.x, qA0.y, qA0.z, qA0.w,
                                  qA1.x, qA1.y, qA1.z, qA1.w,
                                  qA2.x, qA2.y, qA2.z, qA2.w};
#pragma unroll
            for (int dx = 0; dx < 9; ++dx) {
                acc[dx].x += a0.x * wv[dx + 0];
                acc[dx].y += a0.y * wv[dx + 1];
                acc[dx].z += a0.z * wv[dx + 2];
                acc[dx].w += a0.w * wv[dx + 3];
            }
            // frags(cc+1): after this body's write (same-wave lgkm ordering)
            qB0 = *(const float4*)(ldr);
            qB1 = *(const float4*)(ldr + 4);
            qB2 = *(const float4*)(ldr + 8);
        }
        // ============ odd body: channel cc+1 ============
        {
#pragma unroll
            for (int k = 0; k < 2; ++k)
                if (sAct[k]) *(float4*)(&lds[sLds[k]]) = stB[k];   // f2(cc+2)

            const float4 a0 = faB;                             // f1(cc+1)
            const int c4  = (cc + 4 < Cn) ? (cc + 4) : (Cn - 1);
            const int c3b = (cc + 3 < Cn) ? (cc + 3) : (Cn - 1);
#pragma unroll
            for (int k = 0; k < 2; ++k)
                stB[k] = sVal[k] ? *(const float4*)(f2sp[k] + (size_t)c4 * HW) : z4;
            faB = *(const float4*)(f1b + (size_t)c3b * HW);

            const float wv[12] = {qB0.x, qB0.y, qB0.z, qB0.w,
                                  qB1.x, qB1.y, qB1.z, qB1.w,
                                  qB2.x, qB2.y, qB2.z, qB2.w};
#pragma unroll
            for (int dx = 0; dx < 9; ++dx) {
                acc[dx].x += a0.x * wv[dx + 0];
                acc[dx].y += a0.y * wv[dx + 1];
                acc[dx].z += a0.z * wv[dx + 2];
                acc[dx].w += a0.w * wv[dx + 3];
            }
            // frags(cc+2)
            qA0 = *(const float4*)(ldr);
            qA1 = *(const float4*)(ldr + 4);
            qA2 = *(const float4*)(ldr + 8);
        }
    }

    // ---- writeout: 9 float4 per thread, coalesced 16B stores ----
    const float sc = 1.0f / 128.0f;
    float* ob = outg + (size_t)n * 81 * HW + (size_t)hA * Ww + wA;
#pragma unroll
    for (int dx = 0; dx < 9; ++dx) {
        const int k = dy * 9 + dx;
        float4 v = acc[dx];
        v.x *= sc; v.y *= sc; v.z *= sc; v.w *= sc;
        *(float4*)(ob + (size_t)k * HW) = v;
    }
}

extern "C" void kernel_launch(void* const* d_in, const int* in_sizes, int n_in,
                              void* d_out, int out_size, void* d_ws, size_t ws_size,
                              hipStream_t stream) {
    const float* f1 = (const float*)d_in[0];
    const float* f2 = (const float*)d_in[1];
    float* out = (float*)d_out;
    // grid: 672 tiles x 9 dy, swizzled so a tile's 9 waves share an XCD
    costvol_kernel<<<dim3(6048), dim3(64), 0, stream>>>(f1, f2, out);
}